// Round 6
// baseline (919.376 us; speedup 1.0000x reference)
//
#include <hip/hip_runtime.h>

#define EPSF 1e-8f

constexpr int F  = 32;
constexpr int K  = 16;
constexpr int C  = 10;
constexpr int FK = F * K;                       // 512
// replica layout (floats): S[FK*C] | SY[FK*C] | mass[FK] | cnt[FK] | ssq[FK] | yqm[1]
constexpr int OFF_S    = 0;
constexpr int OFF_SY   = FK * C;                // 5120
constexpr int OFF_MASS = 2 * FK * C;            // 10240
constexpr int OFF_CNT  = OFF_MASS + FK;         // 10752
constexpr int OFF_SSQ  = OFF_CNT + FK;          // 11264
constexpr int OFF_YQM  = OFF_SSQ + FK;          // 11776
constexpr int REP      = OFF_YQM + 1;           // 11777
constexpr int RG       = 16;                    // replica reduction groups

// ---------------------------------------------------------------------------
// K1: single pass over membership. Block = 512 threads = 2 n-lanes x 256 slots.
// slot s handles (f = s>>3, k2 = (s&7)*2) -> two k values via one float2 load.
// h = t>>8 is wave-uniform (waves 0-3 -> h=0, waves 4-7 -> h=1).
// __launch_bounds__(512, 2): min 2 waves/EU (= the 1-block/CU residency) lifts
// the RA's VGPR cap to 256. R5 profile showed the default heuristic capped at
// 40 VGPR and spilled all 46 accumulators to scratch: WRITE_SIZE 1.67 GB vs
// 24 MB expected, VALUBusy 6%, 720 us. ~85 live VGPRs must stay in registers.
// ---------------------------------------------------------------------------
__global__ __launch_bounds__(512, 2) void k1_accum(const float* __restrict__ mem,
                                                   const float* __restrict__ yp,
                                                   float* __restrict__ ws,
                                                   int N, int chunk)
{
    const int t    = threadIdx.x;
    const int slot = t & 255;
    const int h    = t >> 8;          // n-lane (uniform per wave)
    const int b    = blockIdx.x;
    const int k2   = (slot & 7) * 2;

    float S0[C], S1[C], Y0[C], Y1[C];
#pragma unroll
    for (int c = 0; c < C; ++c) { S0[c] = 0.f; S1[c] = 0.f; Y0[c] = 0.f; Y1[c] = 0.f; }
    float mass0 = 0.f, mass1 = 0.f, cnt0 = 0.f, cnt1 = 0.f, ssq0 = 0.f, ssq1 = 0.f;
    float yqm = 0.f;

    const int start = b * chunk;
    const int end   = min(N, start + chunk);

    auto compute = [&](int n, float2 m) {
        // teacher row: n is wave-uniform -> scalar (SMEM) loads
        const int ns = __builtin_amdgcn_readfirstlane(n);
        float yv[C];
#pragma unroll
        for (int c = 0; c < C; ++c) yv[c] = yp[(size_t)ns * C + c];
        float ysq = 0.f;
#pragma unroll
        for (int c = 0; c < C; ++c) ysq += yv[c] * yv[c];

#pragma unroll
        for (int c = 0; c < C; ++c) { S0[c] += m.x * yv[c]; S1[c] += m.y * yv[c]; }
        mass0 += m.x; mass1 += m.y;
        yqm   += (m.x + m.y) * ysq;

        // argmax over the 16 k's of this f (2 per thread x 8 lanes), lowest-k ties.
        // f-groups are 8 consecutive lanes, 8-aligned -> xor offsets 1,2,4 stay in-group.
        float bm; int bk;
        if (m.y > m.x) { bm = m.y; bk = k2 + 1; } else { bm = m.x; bk = k2; }
#pragma unroll
        for (int off = 1; off < 8; off <<= 1) {
            float om = __shfl_xor(bm, off);
            int   ok = __shfl_xor(bk, off);
            if (om > bm || (om == bm && ok < bk)) { bm = om; bk = ok; }
        }
        if (bk == k2) {
            cnt0 += 1.f; ssq0 += ysq;
#pragma unroll
            for (int c = 0; c < C; ++c) Y0[c] += yv[c];
        } else if (bk == k2 + 1) {
            cnt1 += 1.f; ssq1 += ysq;
#pragma unroll
            for (int c = 0; c < C; ++c) Y1[c] += yv[c];
        }
    };

    auto ldm = [&](int n) {
        return *reinterpret_cast<const float2*>(mem + (size_t)n * FK + (size_t)slot * 2);
    };

    int n0 = start;
    for (; n0 + 7 < end; n0 += 8) {           // 8 consecutive n per block-iter
        // issue all 4 loads first -> 32 B/lane in flight
        const float2 m0 = ldm(n0 + h);
        const float2 m1 = ldm(n0 + 2 + h);
        const float2 m2 = ldm(n0 + 4 + h);
        const float2 m3 = ldm(n0 + 6 + h);
        compute(n0 + h,     m0);
        compute(n0 + 2 + h, m1);
        compute(n0 + 4 + h, m2);
        compute(n0 + 6 + h, m3);
    }
    for (; n0 < end; n0 += 2) {
        const int n = n0 + h;                 // wave-uniform guard
        if (n < end) compute(n, ldm(n));
    }

    // ---- yqm: reduce over all 512 threads ----
    __shared__ float wsum[8];
    float yq = yqm;
#pragma unroll
    for (int off = 1; off < 64; off <<= 1) yq += __shfl_xor(yq, off);
    if ((t & 63) == 0) wsum[t >> 6] = yq;

    // ---- combine the two n-halves via LDS (h=1 writes, h=0 adds+stores) ----
    __shared__ float lds[256 * 46];           // 47104 B
    if (h == 1) {
        float* q = &lds[slot * 46];
#pragma unroll
        for (int c = 0; c < C; ++c) {
            q[c]      = S0[c];  q[10 + c] = S1[c];
            q[20 + c] = Y0[c];  q[30 + c] = Y1[c];
        }
        q[40] = mass0; q[41] = mass1;
        q[42] = cnt0;  q[43] = cnt1;
        q[44] = ssq0;  q[45] = ssq1;
    }
    __syncthreads();

    float* rep = ws + (size_t)b * REP;
    if (t == 0) {
        float s = 0.f;
        for (int w = 0; w < 8; ++w) s += wsum[w];
        rep[OFF_YQM] = s;
    }
    if (h == 0) {
        const float* q = &lds[slot * 46];
        const int fk0 = slot * 2, fk1 = slot * 2 + 1;
#pragma unroll
        for (int c = 0; c < C; ++c) {
            rep[OFF_S  + fk0 * C + c] = S0[c] + q[c];
            rep[OFF_S  + fk1 * C + c] = S1[c] + q[10 + c];
            rep[OFF_SY + fk0 * C + c] = Y0[c] + q[20 + c];
            rep[OFF_SY + fk1 * C + c] = Y1[c] + q[30 + c];
        }
        rep[OFF_MASS + fk0] = mass0 + q[40]; rep[OFF_MASS + fk1] = mass1 + q[41];
        rep[OFF_CNT  + fk0] = cnt0  + q[42]; rep[OFF_CNT  + fk1] = cnt1  + q[43];
        rep[OFF_SSQ  + fk0] = ssq0  + q[44]; rep[OFF_SSQ  + fk1] = ssq1  + q[45];
    }
}

// ---------------------------------------------------------------------------
// K2: partial[g][e] = sum over replica-chunk g of ws[r*REP + e]
// grid = (ceil(REP/256), RG) -> 16x the in-flight loads of a flat reduction.
// ---------------------------------------------------------------------------
__global__ __launch_bounds__(256) void k2_reduce(const float* __restrict__ ws,
                                                 float* __restrict__ partial,
                                                 int G, int CH)
{
    const int e = blockIdx.x * 256 + threadIdx.x;
    if (e >= REP) return;
    const int g  = blockIdx.y;
    const int r0 = g * CH;
    const int r1 = min(G, r0 + CH);
    float s0 = 0.f, s1 = 0.f, s2 = 0.f, s3 = 0.f;
    int r = r0;
    for (; r + 3 < r1; r += 4) {
        s0 += ws[(size_t)(r + 0) * REP + e];
        s1 += ws[(size_t)(r + 1) * REP + e];
        s2 += ws[(size_t)(r + 2) * REP + e];
        s3 += ws[(size_t)(r + 3) * REP + e];
    }
    for (; r < r1; ++r) s0 += ws[(size_t)r * REP + e];
    partial[(size_t)g * REP + e] = (s0 + s1) + (s2 + s3);
}

// ---------------------------------------------------------------------------
// K2b: red[e] = sum over the RG partials (753 KB total, trivially fast)
// ---------------------------------------------------------------------------
__global__ __launch_bounds__(256) void k2b_collapse(const float* __restrict__ partial,
                                                    float* __restrict__ red)
{
    const int e = blockIdx.x * 256 + threadIdx.x;
    if (e >= REP) return;
    float s = 0.f;
#pragma unroll
    for (int g = 0; g < RG; ++g) s += partial[(size_t)g * REP + e];
    red[e] = s;
}

// ---------------------------------------------------------------------------
// K3: final tiny math; one block, thread = (f,k)
// ---------------------------------------------------------------------------
__global__ __launch_bounds__(512) void k3_final(const float* __restrict__ red,
                                                float* __restrict__ out, float Nf)
{
    const int t = threadIdx.x;          // fk
    const int k = t & (K - 1);

    const float* Sa = red + OFF_S;
    const float* Ya = red + OFF_SY;
    const float* Ma = red + OFF_MASS;
    const float* Ca = red + OFF_CNT;
    const float* Qa = red + OFF_SSQ;
    const float  yqm = red[OFF_YQM];

    // ---- soft ----
    const float massr = Ma[t];
    const float bmass = massr + EPSF;
    float cen[C], csq = 0.f, Cp = 0.f;
#pragma unroll
    for (int c = 0; c < C; ++c) {
        const float s  = Sa[t * C + c];
        const float cc = s / bmass;
        cen[c] = cc; csq += cc * cc; Cp += cc * s;
    }
    const float q1 = csq * massr - 2.f * Cp;   // contributes (B - 2C)

    __shared__ float sC[FK][C];
#pragma unroll
    for (int c = 0; c < C; ++c) sC[t][c] = cen[c];
    __syncthreads();
    float interp = 0.f;
    if (k < K - 1) {
#pragma unroll
        for (int c = 0; c < C; ++c) { const float d = cen[c] - sC[t + 1][c]; interp += d * d; }
    }

    // ---- hard ----
    const float cntv = Ca[t];
    const float safe = fmaxf(cntv, 1.f);
    float cenh[C], csqh = 0.f;
#pragma unroll
    for (int c = 0; c < C; ++c) { const float v = Ya[t * C + c] / safe; cenh[c] = v; csqh += v * v; }
    const float binv  = (cntv > 1.f) ? (Qa[t] / safe - csqh) : 0.f;
    const float valid = (cntv > 1.f) ? 1.f : 0.f;
    const float m1    = (cntv >= 1.f) ? 1.f : 0.f;

    // per-f reductions over the 16 k-lanes (16-aligned lane groups)
    float M = m1;
#pragma unroll
    for (int off = 1; off < 16; off <<= 1) M += __shfl_xor(M, off);
    const float safeM = fmaxf(M, 1.f);
    float dev2 = 0.f;
#pragma unroll
    for (int c = 0; c < C; ++c) {
        float v = cenh[c] * m1;
#pragma unroll
        for (int off = 1; off < 16; off <<= 1) v += __shfl_xor(v, off);
        const float d = (cenh[c] - v / safeM) * m1;
        dev2 += d * d;
    }
#pragma unroll
    for (int off = 1; off < 16; off <<= 1) dev2 += __shfl_xor(dev2, off);
    const float cvar  = (M > 1.f) ? dev2 / safeM : 0.f;
    const float cvar0 = (k == 0) ? cvar : 0.f;

    // ---- block reduce {q1, interp, binv, valid, cvar0} ----
    float vals[5] = { q1, interp, binv, valid, cvar0 };
    __shared__ float rbuf[8][5];
#pragma unroll
    for (int i = 0; i < 5; ++i) {
        float v = vals[i];
#pragma unroll
        for (int off = 1; off < 64; off <<= 1) v += __shfl_xor(v, off);
        if ((t & 63) == 0) rbuf[t >> 6][i] = v;
    }
    __syncthreads();
    if (t == 0) {
        float s[5] = {0.f, 0.f, 0.f, 0.f, 0.f};
        for (int w = 0; w < 8; ++w)
            for (int i = 0; i < 5; ++i) s[i] += rbuf[w][i];
        const float loss_intra = (yqm + s[0]) / Nf;
        const float loss_inter = -s[1] / (float)F;
        const float intra_var  = s[2] / (s[3] + EPSF);
        const float inter_var  = s[4] / (float)F;
        out[0] = loss_intra + 3.f * loss_inter;
        out[1] = loss_intra;
        out[2] = loss_inter;
        out[3] = intra_var;
        out[4] = inter_var;
    }
}

extern "C" void kernel_launch(void* const* d_in, const int* in_sizes, int n_in,
                              void* d_out, int out_size, void* d_ws, size_t ws_size,
                              hipStream_t stream)
{
    (void)n_in; (void)out_size;
    const float* mem = (const float*)d_in[0];
    const float* yp  = (const float*)d_in[1];
    float* out = (float*)d_out;
    const int N = in_sizes[0] / FK;            // 100000

    int G = 512;                               // replicas = blocks for K1 (2 blocks/CU)
    {
        const size_t need = ((size_t)G + RG + 1) * REP * sizeof(float);
        if (need > ws_size) {
            G = (int)(ws_size / sizeof(float) / REP) - (RG + 1);
            if (G < 1) G = 1;
            if (G > 512) G = 512;
        }
    }
    float* ws      = (float*)d_ws;
    float* partial = ws + (size_t)G * REP;
    float* red     = partial + (size_t)RG * REP;
    const int chunk = (N + G - 1) / G;
    const int CH    = (G + RG - 1) / RG;

    k1_accum<<<G, 512, 0, stream>>>(mem, yp, ws, N, chunk);
    k2_reduce<<<dim3((REP + 255) / 256, RG), 256, 0, stream>>>(ws, partial, G, CH);
    k2b_collapse<<<(REP + 255) / 256, 256, 0, stream>>>(partial, red);
    k3_final<<<1, 512, 0, stream>>>(red, out, (float)N);
}

// Round 9
// 328.848 us; speedup vs baseline: 2.7958x; 2.7958x over previous
//
#include <hip/hip_runtime.h>

#define EPSF 1e-8f

constexpr int F  = 32;
constexpr int K  = 16;
constexpr int C  = 10;
constexpr int FK = F * K;                       // 512
// replica layout (floats): S[FK*C] | SY[FK*C] | mass[FK] | cnt[FK] | ssq[FK] | yqm[1]
constexpr int OFF_S    = 0;
constexpr int OFF_SY   = FK * C;                // 5120
constexpr int OFF_MASS = 2 * FK * C;            // 10240
constexpr int OFF_CNT  = OFF_MASS + FK;         // 10752
constexpr int OFF_SSQ  = OFF_CNT + FK;          // 11264
constexpr int OFF_YQM  = OFF_SSQ + FK;          // 11776
constexpr int REP      = OFF_YQM + 1;           // 11777
constexpr int RG       = 16;                    // replica reduction groups

typedef float f32x10 __attribute__((ext_vector_type(10)));

// One n-step of K1. Macro (not lambda): R5/R6 profiles showed the lambda
// version kept the accumulator arrays in scratch (VGPR=40, 1.67 GB scratch
// write traffic, 720 us). ext_vector + macro keeps all state in VGPRs.
#define K1_STEP(NN, MM) do {                                              \
    const int ns_ = __builtin_amdgcn_readfirstlane(NN);                   \
    const float* yr_ = yp + (size_t)ns_ * C;                              \
    f32x10 yv_;                                                           \
    _Pragma("unroll")                                                     \
    for (int c = 0; c < C; ++c) yv_[c] = yr_[c];                          \
    float ysq_ = 0.f;                                                     \
    _Pragma("unroll")                                                     \
    for (int c = 0; c < C; ++c) ysq_ += yv_[c] * yv_[c];                  \
    _Pragma("unroll")                                                     \
    for (int c = 0; c < C; ++c) { S0[c] += (MM).x * yv_[c];               \
                                  S1[c] += (MM).y * yv_[c]; }             \
    mass0 += (MM).x; mass1 += (MM).y;                                     \
    yqm   += ((MM).x + (MM).y) * ysq_;                                    \
    float bm_; int bk_;                                                   \
    if ((MM).y > (MM).x) { bm_ = (MM).y; bk_ = k2 + 1; }                  \
    else                 { bm_ = (MM).x; bk_ = k2;     }                  \
    _Pragma("unroll")                                                     \
    for (int off = 1; off < 8; off <<= 1) {                               \
        const float om_ = __shfl_xor(bm_, off);                           \
        const int   ok_ = __shfl_xor(bk_, off);                           \
        if (om_ > bm_ || (om_ == bm_ && ok_ < bk_)) { bm_ = om_; bk_ = ok_; } \
    }                                                                     \
    if (bk_ == k2) {                                                      \
        cnt0 += 1.f; ssq0 += ysq_;                                        \
        _Pragma("unroll")                                                 \
        for (int c = 0; c < C; ++c) Y0[c] += yv_[c];                      \
    } else if (bk_ == k2 + 1) {                                           \
        cnt1 += 1.f; ssq1 += ysq_;                                        \
        _Pragma("unroll")                                                 \
        for (int c = 0; c < C; ++c) Y1[c] += yv_[c];                      \
    }                                                                     \
} while (0)

// ---------------------------------------------------------------------------
// K1: single pass over membership. Block = 512 threads = 2 n-lanes x 256 slots.
// slot s handles (f = s>>3, k2 = (s&7)*2) -> two k values via one float2 load.
// h = t>>8 is wave-uniform (waves 0-3 -> h=0, waves 4-7 -> h=1).
// ---------------------------------------------------------------------------
__global__ __launch_bounds__(512, 2) void k1_accum(const float* __restrict__ mem,
                                                   const float* __restrict__ yp,
                                                   float* __restrict__ ws,
                                                   int N, int chunk)
{
    const int t    = threadIdx.x;
    const int slot = t & 255;
    const int h    = t >> 8;          // n-lane (uniform per wave)
    const int b    = blockIdx.x;
    const int k2   = (slot & 7) * 2;

    f32x10 S0, S1, Y0, Y1;
#pragma unroll
    for (int c = 0; c < C; ++c) { S0[c] = 0.f; S1[c] = 0.f; Y0[c] = 0.f; Y1[c] = 0.f; }
    float mass0 = 0.f, mass1 = 0.f, cnt0 = 0.f, cnt1 = 0.f, ssq0 = 0.f, ssq1 = 0.f;
    float yqm = 0.f;

    const int start = b * chunk;
    const int end   = min(N, start + chunk);
    const float* mslot = mem + (size_t)slot * 2;

    int n0 = start;
    for (; n0 + 7 < end; n0 += 8) {           // 8 consecutive n per block-iter
        // issue all 4 loads first -> 32 B/lane in flight
        const float2 m0 = *reinterpret_cast<const float2*>(mslot + (size_t)(n0 + h)     * FK);
        const float2 m1 = *reinterpret_cast<const float2*>(mslot + (size_t)(n0 + 2 + h) * FK);
        const float2 m2 = *reinterpret_cast<const float2*>(mslot + (size_t)(n0 + 4 + h) * FK);
        const float2 m3 = *reinterpret_cast<const float2*>(mslot + (size_t)(n0 + 6 + h) * FK);
        K1_STEP(n0 + h,     m0);
        K1_STEP(n0 + 2 + h, m1);
        K1_STEP(n0 + 4 + h, m2);
        K1_STEP(n0 + 6 + h, m3);
    }
    for (; n0 < end; n0 += 2) {
        const int n = n0 + h;                 // wave-uniform guard
        if (n < end) {
            const float2 mt = *reinterpret_cast<const float2*>(mslot + (size_t)n * FK);
            K1_STEP(n, mt);
        }
    }

    // ---- yqm: reduce over all 512 threads ----
    __shared__ float wsum[8];
    float yq = yqm;
#pragma unroll
    for (int off = 1; off < 64; off <<= 1) yq += __shfl_xor(yq, off);
    if ((t & 63) == 0) wsum[t >> 6] = yq;

    // ---- combine the two n-halves via LDS (h=1 writes, h=0 adds+stores) ----
    __shared__ float lds[256 * 46];           // 47104 B
    if (h == 1) {
        float* q = &lds[slot * 46];
#pragma unroll
        for (int c = 0; c < C; ++c) {
            q[c]      = S0[c];  q[10 + c] = S1[c];
            q[20 + c] = Y0[c];  q[30 + c] = Y1[c];
        }
        q[40] = mass0; q[41] = mass1;
        q[42] = cnt0;  q[43] = cnt1;
        q[44] = ssq0;  q[45] = ssq1;
    }
    __syncthreads();

    float* rep = ws + (size_t)b * REP;
    if (t == 0) {
        float s = 0.f;
        for (int w = 0; w < 8; ++w) s += wsum[w];
        rep[OFF_YQM] = s;
    }
    if (h == 0) {
        const float* q = &lds[slot * 46];
        const int fk0 = slot * 2, fk1 = slot * 2 + 1;
#pragma unroll
        for (int c = 0; c < C; ++c) {
            rep[OFF_S  + fk0 * C + c] = S0[c] + q[c];
            rep[OFF_S  + fk1 * C + c] = S1[c] + q[10 + c];
            rep[OFF_SY + fk0 * C + c] = Y0[c] + q[20 + c];
            rep[OFF_SY + fk1 * C + c] = Y1[c] + q[30 + c];
        }
        rep[OFF_MASS + fk0] = mass0 + q[40]; rep[OFF_MASS + fk1] = mass1 + q[41];
        rep[OFF_CNT  + fk0] = cnt0  + q[42]; rep[OFF_CNT  + fk1] = cnt1  + q[43];
        rep[OFF_SSQ  + fk0] = ssq0  + q[44]; rep[OFF_SSQ  + fk1] = ssq1  + q[45];
    }
}

// ---------------------------------------------------------------------------
// K2: partial[g][e] = sum over replica-chunk g of ws[r*REP + e]
// grid = (ceil(REP/256), RG) -> 16x the in-flight loads of a flat reduction.
// ---------------------------------------------------------------------------
__global__ __launch_bounds__(256) void k2_reduce(const float* __restrict__ ws,
                                                 float* __restrict__ partial,
                                                 int G, int CH)
{
    const int e = blockIdx.x * 256 + threadIdx.x;
    if (e >= REP) return;
    const int g  = blockIdx.y;
    const int r0 = g * CH;
    const int r1 = min(G, r0 + CH);
    float s0 = 0.f, s1 = 0.f, s2 = 0.f, s3 = 0.f;
    int r = r0;
    for (; r + 3 < r1; r += 4) {
        s0 += ws[(size_t)(r + 0) * REP + e];
        s1 += ws[(size_t)(r + 1) * REP + e];
        s2 += ws[(size_t)(r + 2) * REP + e];
        s3 += ws[(size_t)(r + 3) * REP + e];
    }
    for (; r < r1; ++r) s0 += ws[(size_t)r * REP + e];
    partial[(size_t)g * REP + e] = (s0 + s1) + (s2 + s3);
}

// ---------------------------------------------------------------------------
// K2b: red[e] = sum over the RG partials (753 KB total, trivially fast)
// ---------------------------------------------------------------------------
__global__ __launch_bounds__(256) void k2b_collapse(const float* __restrict__ partial,
                                                    float* __restrict__ red)
{
    const int e = blockIdx.x * 256 + threadIdx.x;
    if (e >= REP) return;
    float s = 0.f;
#pragma unroll
    for (int g = 0; g < RG; ++g) s += partial[(size_t)g * REP + e];
    red[e] = s;
}

// ---------------------------------------------------------------------------
// K3: final tiny math; one block, thread = (f,k)
// ---------------------------------------------------------------------------
__global__ __launch_bounds__(512) void k3_final(const float* __restrict__ red,
                                                float* __restrict__ out, float Nf)
{
    const int t = threadIdx.x;          // fk
    const int k = t & (K - 1);

    const float* Sa = red + OFF_S;
    const float* Ya = red + OFF_SY;
    const float* Ma = red + OFF_MASS;
    const float* Ca = red + OFF_CNT;
    const float* Qa = red + OFF_SSQ;
    const float  yqm = red[OFF_YQM];

    // ---- soft ----
    const float massr = Ma[t];
    const float bmass = massr + EPSF;
    float cen[C], csq = 0.f, Cp = 0.f;
#pragma unroll
    for (int c = 0; c < C; ++c) {
        const float s  = Sa[t * C + c];
        const float cc = s / bmass;
        cen[c] = cc; csq += cc * cc; Cp += cc * s;
    }
    const float q1 = csq * massr - 2.f * Cp;   // contributes (B - 2C)

    __shared__ float sC[FK][C];
#pragma unroll
    for (int c = 0; c < C; ++c) sC[t][c] = cen[c];
    __syncthreads();
    float interp = 0.f;
    if (k < K - 1) {
#pragma unroll
        for (int c = 0; c < C; ++c) { const float d = cen[c] - sC[t + 1][c]; interp += d * d; }
    }

    // ---- hard ----
    const float cntv = Ca[t];
    const float safe = fmaxf(cntv, 1.f);
    float cenh[C], csqh = 0.f;
#pragma unroll
    for (int c = 0; c < C; ++c) { const float v = Ya[t * C + c] / safe; cenh[c] = v; csqh += v * v; }
    const float binv  = (cntv > 1.f) ? (Qa[t] / safe - csqh) : 0.f;
    const float valid = (cntv > 1.f) ? 1.f : 0.f;
    const float m1    = (cntv >= 1.f) ? 1.f : 0.f;

    // per-f reductions over the 16 k-lanes (16-aligned lane groups)
    float M = m1;
#pragma unroll
    for (int off = 1; off < 16; off <<= 1) M += __shfl_xor(M, off);
    const float safeM = fmaxf(M, 1.f);
    float dev2 = 0.f;
#pragma unroll
    for (int c = 0; c < C; ++c) {
        float v = cenh[c] * m1;
#pragma unroll
        for (int off = 1; off < 16; off <<= 1) v += __shfl_xor(v, off);
        const float d = (cenh[c] - v / safeM) * m1;
        dev2 += d * d;
    }
#pragma unroll
    for (int off = 1; off < 16; off <<= 1) dev2 += __shfl_xor(dev2, off);
    const float cvar  = (M > 1.f) ? dev2 / safeM : 0.f;
    const float cvar0 = (k == 0) ? cvar : 0.f;

    // ---- block reduce {q1, interp, binv, valid, cvar0} ----
    float vals[5] = { q1, interp, binv, valid, cvar0 };
    __shared__ float rbuf[8][5];
#pragma unroll
    for (int i = 0; i < 5; ++i) {
        float v = vals[i];
#pragma unroll
        for (int off = 1; off < 64; off <<= 1) v += __shfl_xor(v, off);
        if ((t & 63) == 0) rbuf[t >> 6][i] = v;
    }
    __syncthreads();
    if (t == 0) {
        float s[5] = {0.f, 0.f, 0.f, 0.f, 0.f};
        for (int w = 0; w < 8; ++w)
            for (int i = 0; i < 5; ++i) s[i] += rbuf[w][i];
        const float loss_intra = (yqm + s[0]) / Nf;
        const float loss_inter = -s[1] / (float)F;
        const float intra_var  = s[2] / (s[3] + EPSF);
        const float inter_var  = s[4] / (float)F;
        out[0] = loss_intra + 3.f * loss_inter;
        out[1] = loss_intra;
        out[2] = loss_inter;
        out[3] = intra_var;
        out[4] = inter_var;
    }
}

extern "C" void kernel_launch(void* const* d_in, const int* in_sizes, int n_in,
                              void* d_out, int out_size, void* d_ws, size_t ws_size,
                              hipStream_t stream)
{
    (void)n_in; (void)out_size;
    const float* mem = (const float*)d_in[0];
    const float* yp  = (const float*)d_in[1];
    float* out = (float*)d_out;
    const int N = in_sizes[0] / FK;            // 100000

    int G = 512;                               // replicas = blocks for K1 (2 blocks/CU)
    {
        const size_t need = ((size_t)G + RG + 1) * REP * sizeof(float);
        if (need > ws_size) {
            G = (int)(ws_size / sizeof(float) / REP) - (RG + 1);
            if (G < 1) G = 1;
            if (G > 512) G = 512;
        }
    }
    float* ws      = (float*)d_ws;
    float* partial = ws + (size_t)G * REP;
    float* red     = partial + (size_t)RG * REP;
    const int chunk = (N + G - 1) / G;
    const int CH    = (G + RG - 1) / RG;

    k1_accum<<<G, 512, 0, stream>>>(mem, yp, ws, N, chunk);
    k2_reduce<<<dim3((REP + 255) / 256, RG), 256, 0, stream>>>(ws, partial, G, CH);
    k2b_collapse<<<(REP + 255) / 256, 256, 0, stream>>>(partial, red);
    k3_final<<<1, 512, 0, stream>>>(red, out, (float)N);
}

// Round 10
// 327.873 us; speedup vs baseline: 2.8041x; 1.0030x over previous
//
#include <hip/hip_runtime.h>

#define EPSF 1e-8f

constexpr int F  = 32;
constexpr int K  = 16;
constexpr int C  = 10;
constexpr int FK = F * K;                       // 512
// replica layout (floats): S[FK*C] | SY[FK*C] | mass[FK] | cnt[FK] | ssq[FK] | yqm[1]
constexpr int OFF_S    = 0;
constexpr int OFF_SY   = FK * C;                // 5120
constexpr int OFF_MASS = 2 * FK * C;            // 10240
constexpr int OFF_CNT  = OFF_MASS + FK;         // 10752
constexpr int OFF_SSQ  = OFF_CNT + FK;          // 11264
constexpr int OFF_YQM  = OFF_SSQ + FK;          // 11776
constexpr int REP      = OFF_YQM + 1;           // 11777
constexpr int RG       = 32;                    // replica reduction groups
constexpr int G1       = 1024;                  // K1 grid (4 blocks/CU)

typedef float f32x10 __attribute__((ext_vector_type(10)));

// Pure-VALU cross-lane via DPP (no LDS pipe, no lgkmcnt — R9 showed the
// ds_swizzle+s_load lgkm chain left k1 latency-bound at 38% VALUBusy).
#define DPPF(x, ctrl) __int_as_float(__builtin_amdgcn_mov_dpp(__float_as_int(x), (ctrl), 0xF, 0xF, true))
#define DPPI(x, ctrl) __builtin_amdgcn_mov_dpp((x), (ctrl), 0xF, 0xF, true)

// Load teacher row n (wave-uniform address -> broadcast vector loads, vmcnt).
// 40B rows are only 8B-aligned -> five float2 loads.
#define LOADY(NN, YV) do {                                                   \
    const float2* yr_ = reinterpret_cast<const float2*>(yp + (size_t)(NN) * C); \
    const float2 a_ = yr_[0], b_ = yr_[1], c2_ = yr_[2], d_ = yr_[3], e_ = yr_[4]; \
    (YV)[0] = a_.x; (YV)[1] = a_.y; (YV)[2] = b_.x; (YV)[3] = b_.y;          \
    (YV)[4] = c2_.x; (YV)[5] = c2_.y; (YV)[6] = d_.x; (YV)[7] = d_.y;        \
    (YV)[8] = e_.x; (YV)[9] = e_.y;                                          \
} while (0)

// One n-step: soft accum + 8-lane-group argmax (DPP butterfly) + hard accum.
// Group = 8 lanes (one f), 8-aligned: xor1 = quad_perm[1,0,3,2] (0xB1),
// xor2 = quad_perm[2,3,0,1] (0x4E), xor4 = row_ror:4 (0x124) / row_ror:12
// (0x12C) selected by lane bit2 (ror crosses the 8-group at lanes 4-7 / 0-3
// respectively; the select keeps only the in-group partner).
#define K1_STEP(MM, YV, YSQ) do {                                            \
    _Pragma("unroll")                                                        \
    for (int c = 0; c < C; ++c) { S0[c] += (MM).x * (YV)[c];                 \
                                  S1[c] += (MM).y * (YV)[c]; }               \
    mass0 += (MM).x; mass1 += (MM).y;                                        \
    yqm   += ((MM).x + (MM).y) * (YSQ);                                      \
    float bm_; int bk_;                                                      \
    if ((MM).y > (MM).x) { bm_ = (MM).y; bk_ = k2 + 1; }                     \
    else                 { bm_ = (MM).x; bk_ = k2;     }                     \
    { const float om_ = DPPF(bm_, 0xB1); const int ok_ = DPPI(bk_, 0xB1);    \
      if (om_ > bm_ || (om_ == bm_ && ok_ < bk_)) { bm_ = om_; bk_ = ok_; } } \
    { const float om_ = DPPF(bm_, 0x4E); const int ok_ = DPPI(bk_, 0x4E);    \
      if (om_ > bm_ || (om_ == bm_ && ok_ < bk_)) { bm_ = om_; bk_ = ok_; } } \
    { const float oa_ = DPPF(bm_, 0x124); const float ob_ = DPPF(bm_, 0x12C); \
      const int   ka_ = DPPI(bk_, 0x124); const int   kb_ = DPPI(bk_, 0x12C); \
      const float om_ = hi4 ? ob_ : oa_;  const int   ok_ = hi4 ? kb_ : ka_; \
      if (om_ > bm_ || (om_ == bm_ && ok_ < bk_)) { bm_ = om_; bk_ = ok_; } } \
    if (bk_ == k2) {                                                         \
        cnt0 += 1.f; ssq0 += (YSQ);                                          \
        _Pragma("unroll")                                                    \
        for (int c = 0; c < C; ++c) Y0[c] += (YV)[c];                        \
    } else if (bk_ == k2 + 1) {                                              \
        cnt1 += 1.f; ssq1 += (YSQ);                                          \
        _Pragma("unroll")                                                    \
        for (int c = 0; c < C; ++c) Y1[c] += (YV)[c];                        \
    }                                                                        \
} while (0)

// ---------------------------------------------------------------------------
// K1: single pass over membership. Block = 256 threads = 256 (f,k-pair) slots,
// no h-split (no LDS combine). Thread t owns fk = {2t, 2t+1}; all lanes of the
// block walk the same n range (teacher loads wave-uniform). Loop body has
// ONLY vmem loads + VALU/DPP — zero lgkm ops.
// ---------------------------------------------------------------------------
__global__ __launch_bounds__(256) void k1_accum(const float* __restrict__ mem,
                                                const float* __restrict__ yp,
                                                float* __restrict__ ws,
                                                int N, int chunk)
{
    const int t     = threadIdx.x;
    const int b     = blockIdx.x;
    const int k2    = (t & 7) * 2;
    const int slot2 = t * 2;
    const bool hi4  = (t & 4) != 0;

    f32x10 S0, S1, Y0, Y1;
#pragma unroll
    for (int c = 0; c < C; ++c) { S0[c] = 0.f; S1[c] = 0.f; Y0[c] = 0.f; Y1[c] = 0.f; }
    float mass0 = 0.f, mass1 = 0.f, cnt0 = 0.f, cnt1 = 0.f, ssq0 = 0.f, ssq1 = 0.f;
    float yqm = 0.f;

    const int start = b * chunk;
    const int end   = min(N, start + chunk);

    int n = start;
    for (; n + 1 < end; n += 2) {
        // all loads issued before compute (2-deep MLP: 16B membership + 80B teacher)
        const float2 ma = *reinterpret_cast<const float2*>(mem + (size_t)n       * FK + slot2);
        const float2 mb = *reinterpret_cast<const float2*>(mem + (size_t)(n + 1) * FK + slot2);
        f32x10 yva, yvb;
        LOADY(n, yva);
        LOADY(n + 1, yvb);
        float ysqa = 0.f, ysqb = 0.f;
#pragma unroll
        for (int c = 0; c < C; ++c) { ysqa += yva[c] * yva[c]; ysqb += yvb[c] * yvb[c]; }
        K1_STEP(ma, yva, ysqa);
        K1_STEP(mb, yvb, ysqb);
    }
    if (n < end) {
        const float2 ma = *reinterpret_cast<const float2*>(mem + (size_t)n * FK + slot2);
        f32x10 yva;
        LOADY(n, yva);
        float ysqa = 0.f;
#pragma unroll
        for (int c = 0; c < C; ++c) ysqa += yva[c] * yva[c];
        K1_STEP(ma, yva, ysqa);
    }

    // ---- yqm: block reduce (epilogue; lgkm here is fine) ----
    __shared__ float wsum[4];
    float yq = yqm;
#pragma unroll
    for (int off = 1; off < 64; off <<= 1) yq += __shfl_xor(yq, off);
    if ((t & 63) == 0) wsum[t >> 6] = yq;
    __syncthreads();

    float* rep = ws + (size_t)b * REP;
    if (t == 0) rep[OFF_YQM] = (wsum[0] + wsum[1]) + (wsum[2] + wsum[3]);

    const int fk0 = slot2, fk1 = slot2 + 1;
#pragma unroll
    for (int c = 0; c < C; ++c) {
        rep[OFF_S  + fk0 * C + c] = S0[c];
        rep[OFF_S  + fk1 * C + c] = S1[c];
        rep[OFF_SY + fk0 * C + c] = Y0[c];
        rep[OFF_SY + fk1 * C + c] = Y1[c];
    }
    rep[OFF_MASS + fk0] = mass0; rep[OFF_MASS + fk1] = mass1;
    rep[OFF_CNT  + fk0] = cnt0;  rep[OFF_CNT  + fk1] = cnt1;
    rep[OFF_SSQ  + fk0] = ssq0;  rep[OFF_SSQ  + fk1] = ssq1;
}

// ---------------------------------------------------------------------------
// K2: partial[g][e] = sum over replica-chunk g of ws[r*REP + e]
// grid = (ceil(REP/256), RG); coalesced across e.
// ---------------------------------------------------------------------------
__global__ __launch_bounds__(256) void k2_reduce(const float* __restrict__ ws,
                                                 float* __restrict__ partial,
                                                 int G, int CH)
{
    const int e = blockIdx.x * 256 + threadIdx.x;
    if (e >= REP) return;
    const int g  = blockIdx.y;
    const int r0 = g * CH;
    const int r1 = min(G, r0 + CH);
    float s0 = 0.f, s1 = 0.f, s2 = 0.f, s3 = 0.f;
    int r = r0;
    for (; r + 3 < r1; r += 4) {
        s0 += ws[(size_t)(r + 0) * REP + e];
        s1 += ws[(size_t)(r + 1) * REP + e];
        s2 += ws[(size_t)(r + 2) * REP + e];
        s3 += ws[(size_t)(r + 3) * REP + e];
    }
    for (; r < r1; ++r) s0 += ws[(size_t)r * REP + e];
    partial[(size_t)g * REP + e] = (s0 + s1) + (s2 + s3);
}

// ---------------------------------------------------------------------------
// K2b: red[e] = sum over the RG partials (1.5 MB total, trivially fast)
// ---------------------------------------------------------------------------
__global__ __launch_bounds__(256) void k2b_collapse(const float* __restrict__ partial,
                                                    float* __restrict__ red)
{
    const int e = blockIdx.x * 256 + threadIdx.x;
    if (e >= REP) return;
    float s = 0.f;
#pragma unroll
    for (int g = 0; g < RG; ++g) s += partial[(size_t)g * REP + e];
    red[e] = s;
}

// ---------------------------------------------------------------------------
// K3: final tiny math; one block, thread = (f,k)
// ---------------------------------------------------------------------------
__global__ __launch_bounds__(512) void k3_final(const float* __restrict__ red,
                                                float* __restrict__ out, float Nf)
{
    const int t = threadIdx.x;          // fk
    const int k = t & (K - 1);

    const float* Sa = red + OFF_S;
    const float* Ya = red + OFF_SY;
    const float* Ma = red + OFF_MASS;
    const float* Ca = red + OFF_CNT;
    const float* Qa = red + OFF_SSQ;
    const float  yqm = red[OFF_YQM];

    // ---- soft ----
    const float massr = Ma[t];
    const float bmass = massr + EPSF;
    float cen[C], csq = 0.f, Cp = 0.f;
#pragma unroll
    for (int c = 0; c < C; ++c) {
        const float s  = Sa[t * C + c];
        const float cc = s / bmass;
        cen[c] = cc; csq += cc * cc; Cp += cc * s;
    }
    const float q1 = csq * massr - 2.f * Cp;   // contributes (B - 2C)

    __shared__ float sC[FK][C];
#pragma unroll
    for (int c = 0; c < C; ++c) sC[t][c] = cen[c];
    __syncthreads();
    float interp = 0.f;
    if (k < K - 1) {
#pragma unroll
        for (int c = 0; c < C; ++c) { const float d = cen[c] - sC[t + 1][c]; interp += d * d; }
    }

    // ---- hard ----
    const float cntv = Ca[t];
    const float safe = fmaxf(cntv, 1.f);
    float cenh[C], csqh = 0.f;
#pragma unroll
    for (int c = 0; c < C; ++c) { const float v = Ya[t * C + c] / safe; cenh[c] = v; csqh += v * v; }
    const float binv  = (cntv > 1.f) ? (Qa[t] / safe - csqh) : 0.f;
    const float valid = (cntv > 1.f) ? 1.f : 0.f;
    const float m1    = (cntv >= 1.f) ? 1.f : 0.f;

    // per-f reductions over the 16 k-lanes (16-aligned lane groups)
    float M = m1;
#pragma unroll
    for (int off = 1; off < 16; off <<= 1) M += __shfl_xor(M, off);
    const float safeM = fmaxf(M, 1.f);
    float dev2 = 0.f;
#pragma unroll
    for (int c = 0; c < C; ++c) {
        float v = cenh[c] * m1;
#pragma unroll
        for (int off = 1; off < 16; off <<= 1) v += __shfl_xor(v, off);
        const float d = (cenh[c] - v / safeM) * m1;
        dev2 += d * d;
    }
#pragma unroll
    for (int off = 1; off < 16; off <<= 1) dev2 += __shfl_xor(dev2, off);
    const float cvar  = (M > 1.f) ? dev2 / safeM : 0.f;
    const float cvar0 = (k == 0) ? cvar : 0.f;

    // ---- block reduce {q1, interp, binv, valid, cvar0} ----
    float vals[5] = { q1, interp, binv, valid, cvar0 };
    __shared__ float rbuf[8][5];
#pragma unroll
    for (int i = 0; i < 5; ++i) {
        float v = vals[i];
#pragma unroll
        for (int off = 1; off < 64; off <<= 1) v += __shfl_xor(v, off);
        if ((t & 63) == 0) rbuf[t >> 6][i] = v;
    }
    __syncthreads();
    if (t == 0) {
        float s[5] = {0.f, 0.f, 0.f, 0.f, 0.f};
        for (int w = 0; w < 8; ++w)
            for (int i = 0; i < 5; ++i) s[i] += rbuf[w][i];
        const float loss_intra = (yqm + s[0]) / Nf;
        const float loss_inter = -s[1] / (float)F;
        const float intra_var  = s[2] / (s[3] + EPSF);
        const float inter_var  = s[4] / (float)F;
        out[0] = loss_intra + 3.f * loss_inter;
        out[1] = loss_intra;
        out[2] = loss_inter;
        out[3] = intra_var;
        out[4] = inter_var;
    }
}

extern "C" void kernel_launch(void* const* d_in, const int* in_sizes, int n_in,
                              void* d_out, int out_size, void* d_ws, size_t ws_size,
                              hipStream_t stream)
{
    (void)n_in; (void)out_size;
    const float* mem = (const float*)d_in[0];
    const float* yp  = (const float*)d_in[1];
    float* out = (float*)d_out;
    const int N = in_sizes[0] / FK;            // 100000

    int G = G1;                                // replicas = blocks for K1
    {
        const size_t need = ((size_t)G + RG + 1) * REP * sizeof(float);
        if (need > ws_size) {
            G = (int)(ws_size / sizeof(float) / REP) - (RG + 1);
            if (G < 1) G = 1;
            if (G > G1) G = G1;
        }
    }
    float* ws      = (float*)d_ws;
    float* partial = ws + (size_t)G * REP;
    float* red     = partial + (size_t)RG * REP;
    const int chunk = (N + G - 1) / G;
    const int CH    = (G + RG - 1) / RG;

    k1_accum<<<G, 256, 0, stream>>>(mem, yp, ws, N, chunk);
    k2_reduce<<<dim3((REP + 255) / 256, RG), 256, 0, stream>>>(ws, partial, G, CH);
    k2b_collapse<<<(REP + 255) / 256, 256, 0, stream>>>(partial, red);
    k3_final<<<1, 512, 0, stream>>>(red, out, (float)N);
}